// Round 5
// baseline (78.073 us; speedup 1.0000x reference)
//
#include <hip/hip_runtime.h>
#include <math.h>

#define NB 2048      // batch
#define LL 32        // seq len
#define DD 256       // embed dim
#define LP 34        // L+2
#define SRH 264      // bf16 row stride for RC (528 B, 16B-aligned)
#define SA 35        // f32 stride for A1/A2

typedef unsigned short u16;
typedef short bf8 __attribute__((ext_vector_type(8)));
typedef float f32x4 __attribute__((ext_vector_type(4)));
typedef float vf2 __attribute__((ext_vector_type(2)));

__device__ __forceinline__ float bfu(u16 h) { return __uint_as_float(((unsigned)h) << 16); }
__device__ __forceinline__ u16 f2bf(float f) {
    unsigned u = __float_as_uint(f);
    u += 0x7fffu + ((u >> 16) & 1u);          // RNE
    return (u16)(u >> 16);
}
__device__ __forceinline__ unsigned cvt_pk_bf(float lo, float hi) {
    unsigned r;
    asm("v_cvt_pk_bf16_f32 %0, %1, %2" : "=v"(r) : "v"(lo), "v"(hi));
    return r;
}

// Gram tile MFMA helper: C[i][j] = sum_k A[i][k]*B[j][k] over K=256, 16x16 tile
__device__ __forceinline__ f32x4 gram8(const u16* __restrict__ A, const u16* __restrict__ B) {
    f32x4 acc = {0.f, 0.f, 0.f, 0.f};
    #pragma unroll
    for (int ks = 0; ks < 8; ++ks) {
        const bf8 a = *(const bf8*)(A + ks * 32);
        const bf8 b = *(const bf8*)(B + ks * 32);
        acc = __builtin_amdgcn_mfma_f32_16x16x32_bf16(a, b, acc, 0, 0, 0);
    }
    return acc;
}

// phase-2 tiles: {aSide, aOff, bSide, bOff}; t<4 cross (write A1), t>=4 self (write nrm)
__device__ static const signed char TB2[8][4] = {
    {0,0,1,0}, {0,0,1,16}, {0,16,1,0}, {0,16,1,16},
    {0,0,0,0}, {0,16,0,16}, {1,0,1,0}, {1,16,1,16}};

// phase-5 tiles: t<6 self, t>=6 cross; row/col offsets {0,16,18} overlap-tile the 34 range
__device__ static const signed char TB5[15][4] = {
    {0,0,0,0}, {0,16,0,16}, {0,18,0,18}, {1,0,1,0}, {1,16,1,16}, {1,18,1,18},
    {0,0,1,0},  {0,0,1,16},  {0,0,1,18},
    {0,16,1,0}, {0,16,1,16}, {0,16,1,18},
    {0,18,1,0}, {0,18,1,16}, {0,18,1,18}};

// pack W0/W1 (32x256 f32) into MFMA B-fragment layout, bf16:
// frag index t = (wsel*16 + ntile)*64 + lane; lane holds W[k0..k0+7][ntile*16 + (lane&15)], k0=(lane>>4)*8
__global__ __launch_bounds__(256)
void pack_w(const float* __restrict__ W0, const float* __restrict__ W1, u16* __restrict__ wp)
{
    const int t = blockIdx.x * 256 + threadIdx.x;   // 0..2047
    const int lane = t & 63, nt = (t >> 6) & 15, wsel = t >> 10;
    const float* W = wsel ? W1 : W0;
    const int col = nt * 16 + (lane & 15);
    const int k0 = (lane >> 4) * 8;
    unsigned d[4];
    #pragma unroll
    for (int q = 0; q < 4; ++q) {
        const u16 lo = f2bf(W[(size_t)(k0 + 2 * q) * DD + col]);
        const u16 hi = f2bf(W[(size_t)(k0 + 2 * q + 1) * DD + col]);
        d[q] = (unsigned)lo | ((unsigned)hi << 16);
    }
    uint4 u; u.x = d[0]; u.y = d[1]; u.z = d[2]; u.w = d[3];
    ((uint4*)wp)[t] = u;
}

__global__ __attribute__((amdgpu_flat_work_group_size(256, 256), amdgpu_waves_per_eu(4, 4)))
void abcnn_fused(const int* __restrict__ s1, const int* __restrict__ s2,
                 const float* __restrict__ embed,
                 const float* __restrict__ c1w, const float* __restrict__ c1b,
                 const float* __restrict__ c2w, const float* __restrict__ c2b,
                 const float* __restrict__ c3w, const float* __restrict__ c3b,
                 const float* __restrict__ fw1, const float* __restrict__ fb1,
                 const float* __restrict__ fw2, const float* __restrict__ fb2,
                 const u16* __restrict__ wpack, float* __restrict__ lgts)
{
    // LDS budget: 35904 + 4760 + 272 = 40936 B -> rounds to 40960 -> 4 blocks/CU
    __shared__ __align__(16) u16 RC[2][LP][SRH];   // rep rows 0..31 -> c rows 0..33 in place, bf16
    __shared__ float AU[LP * SA];                  // A1 (32x32) then A2 (34x34), stride 35; then UN overlay
    __shared__ float nrm[2][LP];                   // row norms

    const int b    = blockIdx.x;
    const int tid  = threadIdx.x;
    const int lane = tid & 63;
    const int wv   = tid >> 6;
    const int c15  = lane & 15;
    const int q4x  = (lane >> 4) * 4;
    const int ko   = (lane >> 4) * 8;

    // ---------- P1: rep = 5-tap(embed[sent]); 128 thr/sentence; scalarized indices ----------
    {
        const float w0 = c1w[0], w1 = c1w[1], w2 = c1w[2], bb = c1b[0];
        const float gm2 = w0 * (1.f/3.f);
        const float gm1 = (w0 + w1) * (1.f/3.f);
        const float g0  = (w0 + w1 + w2) * (1.f/3.f);
        const float gp1 = (w1 + w2) * (1.f/3.f);
        const float gp2 = w2 * (1.f/3.f);
        const int s  = __builtin_amdgcn_readfirstlane(tid >> 7);  // wave-uniform sentence select
        const int dp = tid & 127;
        const int* sent = (s ? s2 : s1) + b * LL;
        int sv[LL];
        #pragma unroll
        for (int j = 0; j < LL; ++j) sv[j] = sent[j];             // SMEM loads, all in flight
        #pragma unroll
        for (int half = 0; half < 2; ++half) {
            const int j0 = half * 16;
            vf2 x[20];                               // raw rows j0-2 .. j0+17 (clipped)
            #pragma unroll
            for (int i = 0; i < 20; ++i) {
                const int rr = j0 - 2 + i;
                if (rr >= 0 && rr < LL)
                    x[i] = *(const vf2*)(embed + (size_t)sv[rr] * DD + 2 * dp);
                else
                    x[i] = (vf2){0.f, 0.f};
            }
            #pragma unroll
            for (int j = 0; j < 16; ++j) {
                vf2 acc = {bb, bb};
                acc += gm2 * x[j];
                acc += gm1 * x[j + 1];
                acc += g0  * x[j + 2];
                acc += gp1 * x[j + 3];
                acc += gp2 * x[j + 4];
                *(unsigned*)&RC[s][j0 + j][2 * dp] = cvt_pk_bf(acc.x, acc.y);
            }
        }
    }
    __syncthreads();

    // ---------- P2: A1 Gram + rep norms, all via MFMA (2 tiles/wave) ----------
    {
        f32x4 h2[2];
        __builtin_amdgcn_s_setprio(1);
        #pragma unroll
        for (int k = 0; k < 2; ++k) {
            const int t  = wv * 2 + k;
            const int sa = TB2[t][0], oa = TB2[t][1], sb = TB2[t][2], ob = TB2[t][3];
            const f32x4 G = gram8(&RC[sa][oa + c15][ko], &RC[sb][ob + c15][ko]);
            h2[k] = G;
            if (t >= 4 && (c15 >> 2) == (lane >> 4)) {   // self tile: diag -> norms
                const int r = c15 & 3;
                const float dv = (r == 0) ? G[0] : (r == 1) ? G[1] : (r == 2) ? G[2] : G[3];
                nrm[sa][oa + c15] = dv;
            }
        }
        __builtin_amdgcn_s_setprio(0);
        __syncthreads();
        #pragma unroll
        for (int k = 0; k < 2; ++k) {
            const int t = wv * 2 + k;
            if (t < 4) {
                const int oa = TB2[t][1], ob = TB2[t][3];
                const f32x4 G = h2[k];
                #pragma unroll
                for (int r = 0; r < 4; ++r) {
                    const int i = oa + q4x + r, j = ob + c15;
                    const float d2 = nrm[0][i] + nrm[1][j] - 2.f * G[r];
                    AU[i * SA + j] = 1.f / (1.f + sqrtf(fmaxf(d2, 0.f)));
                }
            }
        }
    }
    __syncthreads();

    // ---------- P4: c = conv(rep) + conv_k(A1)@W + c3b; A-frags built once from f32 A1 ----------
    {
        const float cw10 = c3w[3], cw11 = c3w[4], cw12 = c3w[5];
        const float cw00 = c3w[0], cw01 = c3w[1], cw02 = c3w[2], cb3 = c3b[0];
        bf8 afr[3];
        #pragma unroll
        for (int rq = 0; rq < 3; ++rq) {
            const int ro = (rq == 0) ? 0 : (rq == 1) ? 16 : 18;
            const int i = ro + c15;
            unsigned pk[4];
            #pragma unroll
            for (int p = 0; p < 4; ++p) {
                float e[2];
                #pragma unroll
                for (int hh = 0; hh < 2; ++hh) {
                    const int m = ko + 2 * p + hh;          // A1 col 0..31
                    float acc = 0.f;
                    if (i >= 2)           acc += cw10 * AU[(i - 2) * SA + m];
                    if (i >= 1 && i < 33) acc += cw11 * AU[(i - 1) * SA + m];
                    if (i < 32)           acc += cw12 * AU[i * SA + m];
                    e[hh] = acc;
                }
                pk[p] = cvt_pk_bf(e[0], e[1]);
            }
            afr[rq] = *(bf8*)&pk[0];
        }
        for (int wsel = 0; wsel < 2; ++wsel) {
            f32x4 acc[12];
            __builtin_amdgcn_s_setprio(1);
            #pragma unroll
            for (int k = 0; k < 12; ++k) {
                const int rq = k >> 2;                       // static
                const int ro = (rq == 0) ? 0 : (rq == 1) ? 16 : 18;
                const int n  = wv + 4 * (k & 3);             // n-tile 0..15
                const bf8 w = *(const bf8*)(wpack + (size_t)((wsel * 16 + n) * 64 + lane) * 8);
                const f32x4 z = {0.f, 0.f, 0.f, 0.f};
                f32x4 d = __builtin_amdgcn_mfma_f32_16x16x32_bf16(afr[rq], w, z, 0, 0, 0);
                const int dcol = n * 16 + c15;
                const int i0 = ro + q4x;
                float tt[6];
                #pragma unroll
                for (int q2 = 0; q2 < 6; ++q2) {
                    const int rr = i0 - 2 + q2;
                    tt[q2] = (rr >= 0 && rr < LL) ? bfu(RC[wsel][rr][dcol]) : 0.f;
                }
                #pragma unroll
                for (int r = 0; r < 4; ++r)
                    d[r] += cb3 + cw00 * tt[r] + cw01 * tt[r + 1] + cw02 * tt[r + 2];
                acc[k] = d;
            }
            __builtin_amdgcn_s_setprio(0);
            __syncthreads();          // all reads of rep[wsel] done
            #pragma unroll
            for (int k = 0; k < 12; ++k) {
                const int rq = k >> 2;
                const int ro = (rq == 0) ? 0 : (rq == 1) ? 16 : 18;
                const int n  = wv + 4 * (k & 3);
                const int dcol = n * 16 + c15;
                const int i0 = ro + q4x;
                const unsigned p01 = cvt_pk_bf(acc[k][0], acc[k][1]);
                const unsigned p23 = cvt_pk_bf(acc[k][2], acc[k][3]);
                RC[wsel][i0    ][dcol] = (u16)p01;
                RC[wsel][i0 + 1][dcol] = (u16)(p01 >> 16);
                RC[wsel][i0 + 2][dcol] = (u16)p23;
                RC[wsel][i0 + 3][dcol] = (u16)(p23 >> 16);
            }
            __syncthreads();
        }
    }

    // ---------- P5: A2 Gram + c norms via MFMA (overlap tiles {0,16,18}) ----------
    {
        f32x4 h5[4];
        __builtin_amdgcn_s_setprio(1);
        #pragma unroll
        for (int k = 0; k < 4; ++k) {
            const int t = wv + 4 * k;
            if (t < 15) {
                const int sa = TB5[t][0], oa = TB5[t][1], sb = TB5[t][2], ob = TB5[t][3];
                const f32x4 G = gram8(&RC[sa][oa + c15][ko], &RC[sb][ob + c15][ko]);
                h5[k] = G;
                if (t < 6 && (c15 >> 2) == (lane >> 4)) {
                    const int r = c15 & 3;
                    const float dv = (r == 0) ? G[0] : (r == 1) ? G[1] : (r == 2) ? G[2] : G[3];
                    nrm[sa][oa + c15] = dv;
                }
            }
        }
        __builtin_amdgcn_s_setprio(0);
        __syncthreads();
        #pragma unroll
        for (int k = 0; k < 4; ++k) {
            const int t = wv + 4 * k;
            if (t >= 6 && t < 15) {
                const int oa = TB5[t][1], ob = TB5[t][3];
                const f32x4 G = h5[k];
                #pragma unroll
                for (int r = 0; r < 4; ++r) {
                    const int i = oa + q4x + r, j = ob + c15;
                    const float d2 = nrm[0][i] + nrm[1][j] - 2.f * G[r];
                    AU[i * SA + j] = 1.f / (1.f + sqrtf(fmaxf(d2, 0.f)));
                }
            }
        }
    }
    __syncthreads();

    // ---------- P6: weighted row/col sums of A2 (regs -> barrier -> overlay into AU[0..67]) ----------
    {
        const float S2 = c2w[0] + c2w[1] + c2w[2];
        const float sc = S2 * (1.f / 102.f);             // (S2/34) * (1/3)
        float p6 = 0.f;
        if (tid < 68) {
            const bool isCol = tid < 34;
            const int p = isCol ? tid : tid - 34;
            float ssum = 0.f;
            for (int q = 0; q < LP; ++q) ssum += AU[isCol ? (p * SA + q) : (q * SA + p)];
            const float cnt = (p == 0 || p == 33) ? 1.f : ((p == 1 || p == 32) ? 2.f : 3.f);
            p6 = ssum * cnt * sc;
        }
        __syncthreads();                                 // A2 reads complete
        if (tid < 68) AU[tid] = p6;                      // wcol[34], wrow[34]
    }
    __syncthreads();

    // ---------- P7: v1/v2 = weighted column sums of c -> AU[68..579] ----------
    {
        const float cb2 = c2b[0];
        float v1 = cb2, v2 = cb2;
        #pragma unroll
        for (int p = 0; p < LP; ++p) {
            v1 += AU[p]      * bfu(RC[0][p][tid]);
            v2 += AU[34 + p] * bfu(RC[1][p][tid]);
        }
        AU[68 + tid]       = v1;
        AU[68 + 256 + tid] = v2;
    }
    __syncthreads();

    // ---------- P8: h = tanh(v @ fw1 + fb1); logits = h @ fw2 + fb2 ----------
    {
        const int u = tid & 63, sg = tid >> 6;
        const float* vv = &AU[68];
        const float* fp = fw1 + (size_t)(sg * 128) * 64 + u;
        float part = 0.f;
        for (int t = 0; t < 128; ++t) part += vv[sg * 128 + t] * fp[(size_t)t * 64];
        AU[580 + tid] = part;
    }
    __syncthreads();
    if (tid < 64) {
        const float hsum = AU[580 + tid] + AU[644 + tid] + AU[708 + tid] + AU[772 + tid] + fb1[tid];
        AU[836 + tid] = tanhf(hsum);
    }
    __syncthreads();
    if (tid < 2) {
        float lg = fb2[tid];
        for (int u2 = 0; u2 < 64; ++u2) lg += AU[836 + u2] * fw2[u2 * 2 + tid];
        lgts[tid * NB + b] = lg;
    }
}

// softmax over dim 0 (across the 2048 batches, per class column)
__global__ __launch_bounds__(1024)
void softmax_dim0(const float* __restrict__ lgts, float* __restrict__ out)
{
    __shared__ float red[17];
    const int tid = threadIdx.x;
    for (int c = 0; c < 2; ++c) {
        const float x0 = lgts[c * NB + tid];
        const float x1 = lgts[c * NB + 1024 + tid];
        float m = fmaxf(x0, x1);
        #pragma unroll
        for (int off = 32; off >= 1; off >>= 1) m = fmaxf(m, __shfl_xor(m, off));
        if ((tid & 63) == 0) red[tid >> 6] = m;
        __syncthreads();
        if (tid == 0) { float t = red[0]; for (int i = 1; i < 16; ++i) t = fmaxf(t, red[i]); red[16] = t; }
        __syncthreads();
        m = red[16];
        const float e0 = expf(x0 - m), e1 = expf(x1 - m);
        float s = e0 + e1;
        #pragma unroll
        for (int off = 32; off >= 1; off >>= 1) s += __shfl_xor(s, off);
        if ((tid & 63) == 0) red[tid >> 6] = s;
        __syncthreads();
        if (tid == 0) { float t = 0.f; for (int i = 0; i < 16; ++i) t += red[i]; red[16] = t; }
        __syncthreads();
        const float inv = 1.f / red[16];
        out[(size_t)tid * 2 + c]          = e0 * inv;
        out[(size_t)(1024 + tid) * 2 + c] = e1 * inv;
        __syncthreads();
    }
}

extern "C" void kernel_launch(void* const* d_in, const int* in_sizes, int n_in,
                              void* d_out, int out_size, void* d_ws, size_t ws_size,
                              hipStream_t stream)
{
    (void)in_sizes; (void)n_in; (void)out_size; (void)ws_size;
    const int*   s1  = (const int*)  d_in[0];
    const int*   s2  = (const int*)  d_in[1];
    const float* emb = (const float*)d_in[2];
    const float* c1w = (const float*)d_in[3];
    const float* c1b = (const float*)d_in[4];
    const float* c2w = (const float*)d_in[5];
    const float* c2b = (const float*)d_in[6];
    const float* c3w = (const float*)d_in[7];
    const float* c3b = (const float*)d_in[8];
    const float* fw1 = (const float*)d_in[11];
    const float* fb1 = (const float*)d_in[12];
    const float* fw2 = (const float*)d_in[13];
    const float* fb2 = (const float*)d_in[14];
    const float* W0  = (const float*)d_in[9];
    const float* W1  = (const float*)d_in[10];
    u16*   wpack = (u16*)d_ws;                             // 32 KB: packed W fragments
    float* lgts  = (float*)((char*)d_ws + 32768);          // 16 KB: logits
    float* out   = (float*)d_out;

    pack_w<<<dim3(8), dim3(256), 0, stream>>>(W0, W1, wpack);
    abcnn_fused<<<dim3(NB), dim3(256), 0, stream>>>(s1, s2, emb, c1w, c1b, c2w, c2b,
                                                    c3w, c3b, fw1, fb1, fw2, fb2,
                                                    wpack, lgts);
    softmax_dim0<<<dim3(1), dim3(1024), 0, stream>>>(lgts, out);
}

// Round 8
// 66.569 us; speedup vs baseline: 1.1728x; 1.1728x over previous
//
#include <hip/hip_runtime.h>
#include <math.h>

#define NB 2048      // batch
#define LL 32        // seq len
#define DD 256       // embed dim
#define LP 34        // L+2
#define SRH 264      // bf16 row stride for RC (528 B, 16B-aligned)
#define SA 35        // f32 stride for A1/A2

typedef unsigned short u16;
typedef short bf8 __attribute__((ext_vector_type(8)));
typedef float f32x4 __attribute__((ext_vector_type(4)));
typedef float vf2 __attribute__((ext_vector_type(2)));

__device__ __forceinline__ float bfu(u16 h) { return __uint_as_float(((unsigned)h) << 16); }
__device__ __forceinline__ u16 f2bf(float f) {
    unsigned u = __float_as_uint(f);
    u += 0x7fffu + ((u >> 16) & 1u);          // RNE
    return (u16)(u >> 16);
}
__device__ __forceinline__ unsigned cvt_pk_bf(float lo, float hi) {
    unsigned r;
    asm("v_cvt_pk_bf16_f32 %0, %1, %2" : "=v"(r) : "v"(lo), "v"(hi));
    return r;
}

// Gram tile MFMA helper: C[i][j] = sum_k A[i][k]*B[j][k] over K=256, 16x16 tile
__device__ __forceinline__ f32x4 gram8(const u16* __restrict__ A, const u16* __restrict__ B) {
    f32x4 acc = {0.f, 0.f, 0.f, 0.f};
    #pragma unroll
    for (int ks = 0; ks < 8; ++ks) {
        const bf8 a = *(const bf8*)(A + ks * 32);
        const bf8 b = *(const bf8*)(B + ks * 32);
        acc = __builtin_amdgcn_mfma_f32_16x16x32_bf16(a, b, acc, 0, 0, 0);
    }
    return acc;
}

// phase-2 tiles: {aSide, aOff, bSide, bOff}; t<4 cross (write A1), t>=4 self (write nrm)
__device__ static const signed char TB2[8][4] = {
    {0,0,1,0}, {0,0,1,16}, {0,16,1,0}, {0,16,1,16},
    {0,0,0,0}, {0,16,0,16}, {1,0,1,0}, {1,16,1,16}};

// phase-5 tiles: t<6 self, t>=6 cross; row/col offsets {0,16,18} overlap-tile the 34 range
__device__ static const signed char TB5[15][4] = {
    {0,0,0,0}, {0,16,0,16}, {0,18,0,18}, {1,0,1,0}, {1,16,1,16}, {1,18,1,18},
    {0,0,1,0},  {0,0,1,16},  {0,0,1,18},
    {0,16,1,0}, {0,16,1,16}, {0,16,1,18},
    {0,18,1,0}, {0,18,1,16}, {0,18,1,18}};

// pack W0/W1 (32x256 f32) into MFMA B-fragment layout, bf16:
// frag index t = (wsel*16 + ntile)*64 + lane; lane holds W[k0..k0+7][ntile*16 + (lane&15)], k0=(lane>>4)*8
__global__ __launch_bounds__(256)
void pack_w(const float* __restrict__ W0, const float* __restrict__ W1, u16* __restrict__ wp)
{
    const int t = blockIdx.x * 256 + threadIdx.x;   // 0..2047
    const int lane = t & 63, nt = (t >> 6) & 15, wsel = t >> 10;
    const float* W = wsel ? W1 : W0;
    const int col = nt * 16 + (lane & 15);
    const int k0 = (lane >> 4) * 8;
    unsigned d[4];
    #pragma unroll
    for (int q = 0; q < 4; ++q) {
        const u16 lo = f2bf(W[(size_t)(k0 + 2 * q) * DD + col]);
        const u16 hi = f2bf(W[(size_t)(k0 + 2 * q + 1) * DD + col]);
        d[q] = (unsigned)lo | ((unsigned)hi << 16);
    }
    uint4 u; u.x = d[0]; u.y = d[1]; u.z = d[2]; u.w = d[3];
    ((uint4*)wp)[t] = u;
}

__global__ __launch_bounds__(256, 4)
void abcnn_fused(const int* __restrict__ s1, const int* __restrict__ s2,
                 const float* __restrict__ embed,
                 const float* __restrict__ c1w, const float* __restrict__ c1b,
                 const float* __restrict__ c2w, const float* __restrict__ c2b,
                 const float* __restrict__ c3w, const float* __restrict__ c3b,
                 const float* __restrict__ fw1, const float* __restrict__ fb1,
                 const float* __restrict__ fw2, const float* __restrict__ fb2,
                 const u16* __restrict__ wpack, float* __restrict__ lgts)
{
    // LDS budget: 35904 + 4760 + 272 = 40936 B -> rounds to 40960 -> 4 blocks/CU
    __shared__ __align__(16) u16 RC[2][LP][SRH];   // rep rows 0..31 -> c rows 0..33 in place, bf16
    __shared__ float AU[LP * SA];                  // A1 (32x32) then A2 (34x34), stride 35; then UN overlay
    __shared__ float nrm[2][LP];                   // row norms

    const int b    = blockIdx.x;
    const int tid  = threadIdx.x;
    const int lane = tid & 63;
    const int wv   = tid >> 6;
    const int c15  = lane & 15;
    const int q4x  = (lane >> 4) * 4;
    const int ko   = (lane >> 4) * 8;

    // ---------- P1: rep = 5-tap(embed[sent]); 128 thr/sentence; indices in SGPRs ----------
    {
        const float w0 = c1w[0], w1 = c1w[1], w2 = c1w[2], bb = c1b[0];
        const float gm2 = w0 * (1.f/3.f);
        const float gm1 = (w0 + w1) * (1.f/3.f);
        const float g0  = (w0 + w1 + w2) * (1.f/3.f);
        const float gp1 = (w1 + w2) * (1.f/3.f);
        const float gp2 = w2 * (1.f/3.f);
        const int s  = __builtin_amdgcn_readfirstlane(tid >> 7);  // wave-uniform sentence select
        const int dp = tid & 127;
        const int* sent = (s ? s2 : s1) + b * LL;
        int sv[LL];
        #pragma unroll
        for (int j = 0; j < LL; ++j) sv[j] = sent[j];             // SMEM loads, all in flight
        #pragma unroll
        for (int half = 0; half < 2; ++half) {
            const int j0 = half * 16;
            vf2 x[20];                               // raw rows j0-2 .. j0+17 (clipped)
            #pragma unroll
            for (int i = 0; i < 20; ++i) {
                const int rr = j0 - 2 + i;
                if (rr >= 0 && rr < LL)
                    x[i] = *(const vf2*)(embed + (size_t)sv[rr] * DD + 2 * dp);
                else
                    x[i] = (vf2){0.f, 0.f};
            }
            #pragma unroll
            for (int j = 0; j < 16; ++j) {
                vf2 acc = {bb, bb};
                acc += gm2 * x[j];
                acc += gm1 * x[j + 1];
                acc += g0  * x[j + 2];
                acc += gp1 * x[j + 3];
                acc += gp2 * x[j + 4];
                *(unsigned*)&RC[s][j0 + j][2 * dp] = cvt_pk_bf(acc.x, acc.y);
            }
        }
    }
    __syncthreads();

    // ---------- P2: A1 Gram + rep norms, all via MFMA (2 tiles/wave) ----------
    {
        f32x4 h2[2];
        __builtin_amdgcn_s_setprio(1);
        #pragma unroll
        for (int k = 0; k < 2; ++k) {
            const int t  = wv * 2 + k;
            const int sa = TB2[t][0], oa = TB2[t][1], sb = TB2[t][2], ob = TB2[t][3];
            const f32x4 G = gram8(&RC[sa][oa + c15][ko], &RC[sb][ob + c15][ko]);
            h2[k] = G;
            if (t >= 4 && (c15 >> 2) == (lane >> 4)) {   // self tile: diag -> norms
                const int r = c15 & 3;
                const float dv = (r == 0) ? G[0] : (r == 1) ? G[1] : (r == 2) ? G[2] : G[3];
                nrm[sa][oa + c15] = dv;
            }
        }
        __builtin_amdgcn_s_setprio(0);
        __syncthreads();
        #pragma unroll
        for (int k = 0; k < 2; ++k) {
            const int t = wv * 2 + k;
            if (t < 4) {
                const int oa = TB2[t][1], ob = TB2[t][3];
                const f32x4 G = h2[k];
                #pragma unroll
                for (int r = 0; r < 4; ++r) {
                    const int i = oa + q4x + r, j = ob + c15;
                    const float d2 = nrm[0][i] + nrm[1][j] - 2.f * G[r];
                    AU[i * SA + j] = 1.f / (1.f + sqrtf(fmaxf(d2, 0.f)));
                }
            }
        }
    }
    __syncthreads();

    // ---------- P4: c = conv(rep) + Bm@W + cb3 (R5-proven math); descending-rq, barrier-free ----------
    // Per (wsel,nidx) column slice: rq=2 reads rep rows 16..31 / writes rows 32..33 only;
    // rq=1 reads 14..31 (intact) / writes 16..31; rq=0 reads 0..15 (intact) / writes 0..15.
    // Reads precede conflicting writes in wave program order; columns wave/nidx-disjoint -> no barriers.
    {
        const float cw10 = c3w[3], cw11 = c3w[4], cw12 = c3w[5];
        const float cw00 = c3w[0], cw01 = c3w[1], cw02 = c3w[2], cb3 = c3b[0];
        bf8 afr[3];                                  // A-frags of Bm = conv_k(A1)
        #pragma unroll
        for (int rq = 0; rq < 3; ++rq) {
            const int ro = (rq == 0) ? 0 : (rq == 1) ? 16 : 18;
            const int i = ro + c15;
            bf8 af;
            #pragma unroll
            for (int j = 0; j < 8; ++j) {
                const int m = ko + j;                // A1 col 0..31
                float acc = 0.f;
                if (i >= 2)           acc += cw10 * AU[(i - 2) * SA + m];
                if (i >= 1 && i < 33) acc += cw11 * AU[(i - 1) * SA + m];
                if (i < 32)           acc += cw12 * AU[i * SA + m];
                af[j] = (short)f2bf(acc);
            }
            afr[rq] = af;
        }
        __builtin_amdgcn_s_setprio(1);
        #pragma unroll
        for (int wsel = 0; wsel < 2; ++wsel) {
            #pragma unroll
            for (int nidx = 0; nidx < 4; ++nidx) {
                const int n = wv + 4 * nidx;         // n-tile 0..15
                const int dcol = n * 16 + c15;
                const bf8 w = *(const bf8*)(wpack + (size_t)((wsel * 16 + n) * 64 + lane) * 8);
                #pragma unroll
                for (int rqd = 0; rqd < 3; ++rqd) {
                    const int rq = 2 - rqd;          // 2, 1, 0
                    const int ro = (rq == 0) ? 0 : (rq == 1) ? 16 : 18;
                    const int i0 = ro + q4x;
                    const f32x4 z = {0.f, 0.f, 0.f, 0.f};
                    f32x4 d4 = __builtin_amdgcn_mfma_f32_16x16x32_bf16(afr[rq], w, z, 0, 0, 0);
                    float tt[6];
                    #pragma unroll
                    for (int q2 = 0; q2 < 6; ++q2) {
                        const int rr = i0 - 2 + q2;
                        tt[q2] = (rr >= 0 && rr < LL) ? bfu(RC[wsel][rr][dcol]) : 0.f;
                    }
                    #pragma unroll
                    for (int r = 0; r < 4; ++r)
                        d4[r] += cb3 + cw00 * tt[r] + cw01 * tt[r + 1] + cw02 * tt[r + 2];
                    const unsigned p01 = cvt_pk_bf(d4[0], d4[1]);
                    const unsigned p23 = cvt_pk_bf(d4[2], d4[3]);
                    if (rq < 2) {                    // rows 0..15 / 16..31, written once
                        RC[wsel][i0    ][dcol] = (u16)p01;
                        RC[wsel][i0 + 1][dcol] = (u16)(p01 >> 16);
                        RC[wsel][i0 + 2][dcol] = (u16)p23;
                        RC[wsel][i0 + 3][dcol] = (u16)(p23 >> 16);
                    } else if (q4x == 12) {          // rq==2: only rows 32,33
                        RC[wsel][32][dcol] = (u16)p23;
                        RC[wsel][33][dcol] = (u16)(p23 >> 16);
                    }
                }
            }
        }
        __builtin_amdgcn_s_setprio(0);
    }
    __syncthreads();

    // ---------- P5: A2 Gram + c norms via MFMA (overlap tiles {0,16,18}) ----------
    {
        f32x4 h5[4];
        __builtin_amdgcn_s_setprio(1);
        #pragma unroll
        for (int k = 0; k < 4; ++k) {
            const int t = wv + 4 * k;
            if (t < 15) {
                const int sa = TB5[t][0], oa = TB5[t][1], sb = TB5[t][2], ob = TB5[t][3];
                const f32x4 G = gram8(&RC[sa][oa + c15][ko], &RC[sb][ob + c15][ko]);
                h5[k] = G;
                if (t < 6 && (c15 >> 2) == (lane >> 4)) {
                    const int r = c15 & 3;
                    const float dv = (r == 0) ? G[0] : (r == 1) ? G[1] : (r == 2) ? G[2] : G[3];
                    nrm[sa][oa + c15] = dv;
                }
            }
        }
        __builtin_amdgcn_s_setprio(0);
        __syncthreads();
        #pragma unroll
        for (int k = 0; k < 4; ++k) {
            const int t = wv + 4 * k;
            if (t >= 6 && t < 15) {
                const int oa = TB5[t][1], ob = TB5[t][3];
                const f32x4 G = h5[k];
                #pragma unroll
                for (int r = 0; r < 4; ++r) {
                    const int i = oa + q4x + r, j = ob + c15;
                    const float d2 = nrm[0][i] + nrm[1][j] - 2.f * G[r];
                    AU[i * SA + j] = 1.f / (1.f + sqrtf(fmaxf(d2, 0.f)));
                }
            }
        }
    }
    __syncthreads();

    // ---------- P6: weighted row/col sums of A2 (regs -> barrier -> overlay into AU[0..67]) ----------
    {
        const float S2 = c2w[0] + c2w[1] + c2w[2];
        const float sc = S2 * (1.f / 102.f);             // (S2/34) * (1/3)
        float p6 = 0.f;
        if (tid < 68) {
            const bool isCol = tid < 34;
            const int p = isCol ? tid : tid - 34;
            float ssum = 0.f;
            for (int q = 0; q < LP; ++q) ssum += AU[isCol ? (p * SA + q) : (q * SA + p)];
            const float cnt = (p == 0 || p == 33) ? 1.f : ((p == 1 || p == 32) ? 2.f : 3.f);
            p6 = ssum * cnt * sc;
        }
        __syncthreads();                                 // A2 reads complete
        if (tid < 68) AU[tid] = p6;                      // wcol[34], wrow[34]
    }
    __syncthreads();

    // ---------- P7: v1/v2 = weighted column sums of c -> AU[68..579] ----------
    {
        const float cb2 = c2b[0];
        float v1 = cb2, v2 = cb2;
        #pragma unroll
        for (int p = 0; p < LP; ++p) {
            v1 += AU[p]      * bfu(RC[0][p][tid]);
            v2 += AU[34 + p] * bfu(RC[1][p][tid]);
        }
        AU[68 + tid]       = v1;
        AU[68 + 256 + tid] = v2;
    }
    __syncthreads();

    // ---------- P8: h = tanh(v @ fw1 + fb1); logits = h @ fw2 + fb2 ----------
    {
        const int u = tid & 63, sg = tid >> 6;
        const float* vv = &AU[68];
        const float* fp = fw1 + (size_t)(sg * 128) * 64 + u;
        float part = 0.f;
        for (int t = 0; t < 128; ++t) part += vv[sg * 128 + t] * fp[(size_t)t * 64];
        AU[580 + tid] = part;
    }
    __syncthreads();
    if (tid < 64) {
        const float hsum = AU[580 + tid] + AU[644 + tid] + AU[708 + tid] + AU[772 + tid] + fb1[tid];
        AU[836 + tid] = tanhf(hsum);
    }
    __syncthreads();
    if (tid < 2) {
        float lg = fb2[tid];
        for (int u2 = 0; u2 < 64; ++u2) lg += AU[836 + u2] * fw2[u2 * 2 + tid];
        lgts[tid * NB + b] = lg;
    }
}

// softmax over dim 0 (across the 2048 batches, per class column)
__global__ __launch_bounds__(1024)
void softmax_dim0(const float* __restrict__ lgts, float* __restrict__ out)
{
    __shared__ float red[17];
    const int tid = threadIdx.x;
    for (int c = 0; c < 2; ++c) {
        const float x0 = lgts[c * NB + tid];
        const float x1 = lgts[c * NB + 1024 + tid];
        float m = fmaxf(x0, x1);
        #pragma unroll
        for (int off = 32; off >= 1; off >>= 1) m = fmaxf(m, __shfl_xor(m, off));
        if ((tid & 63) == 0) red[tid >> 6] = m;
        __syncthreads();
        if (tid == 0) { float t = red[0]; for (int i = 1; i < 16; ++i) t = fmaxf(t, red[i]); red[16] = t; }
        __syncthreads();
        m = red[16];
        const float e0 = expf(x0 - m), e1 = expf(x1 - m);
        float s = e0 + e1;
        #pragma unroll
        for (int off = 32; off >= 1; off >>= 1) s += __shfl_xor(s, off);
        if ((tid & 63) == 0) red[tid >> 6] = s;
        __syncthreads();
        if (tid == 0) { float t = 0.f; for (int i = 0; i < 16; ++i) t += red[i]; red[16] = t; }
        __syncthreads();
        const float inv = 1.f / red[16];
        out[(size_t)tid * 2 + c]          = e0 * inv;
        out[(size_t)(1024 + tid) * 2 + c] = e1 * inv;
        __syncthreads();
    }
}

extern "C" void kernel_launch(void* const* d_in, const int* in_sizes, int n_in,
                              void* d_out, int out_size, void* d_ws, size_t ws_size,
                              hipStream_t stream)
{
    (void)in_sizes; (void)n_in; (void)out_size; (void)ws_size;
    const int*   s1  = (const int*)  d_in[0];
    const int*   s2  = (const int*)  d_in[1];
    const float* emb = (const float*)d_in[2];
    const float* c1w = (const float*)d_in[3];
    const float* c1b = (const float*)d_in[4];
    const float* c2w = (const float*)d_in[5];
    const float* c2b = (const float*)d_in[6];
    const float* c3w = (const float*)d_in[7];
    const float* c3b = (const float*)d_in[8];
    const float* fw1 = (const float*)d_in[11];
    const float* fb1 = (const float*)d_in[12];
    const float* fw2 = (const float*)d_in[13];
    const float* fb2 = (const float*)d_in[14];
    const float* W0  = (const float*)d_in[9];
    const float* W1  = (const float*)d_in[10];
    u16*   wpack = (u16*)d_ws;                             // 32 KB: packed W fragments
    float* lgts  = (float*)((char*)d_ws + 32768);          // 16 KB: logits
    float* out   = (float*)d_out;

    pack_w<<<dim3(8), dim3(256), 0, stream>>>(W0, W1, wpack);
    abcnn_fused<<<dim3(NB), dim3(256), 0, stream>>>(s1, s2, emb, c1w, c1b, c2w, c2b,
                                                    c3w, c3b, fw1, fb1, fw2, fb2,
                                                    wpack, lgts);
    softmax_dim0<<<dim3(1), dim3(1024), 0, stream>>>(lgts, out);
}